// Round 19
// baseline (284.481 us; speedup 1.0000x reference)
//
#include <hip/hip_runtime.h>
#include <hip/hip_bf16.h>
#include <stdint.h>

typedef __attribute__((ext_vector_type(8))) short short8;
typedef __attribute__((ext_vector_type(4))) float f32x4;
typedef __hip_bfloat16 bf16;

#define AS1 __attribute__((address_space(1)))
#define AS3 __attribute__((address_space(3)))

__device__ __forceinline__ void gl16(const void* g, void* l) {
  __builtin_amdgcn_global_load_lds((const AS1 unsigned int*)g,
                                   (AS3 unsigned int*)l, 16, 0, 0);
}

__device__ __forceinline__ unsigned short bfbits(float x) {
  union { bf16 b; unsigned short u; } c; c.b = __float2bfloat16(x); return c.u;
}

#define SCHED0 __builtin_amdgcn_sched_barrier(0)

// ---------------- fp32 -> bf16 convert (vectorized) ----------------
__global__ __launch_bounds__(256) void k_cvt(const float* __restrict__ src,
                                             bf16* __restrict__ dst, int n8) {
  int i = blockIdx.x * blockDim.x + threadIdx.x;
  int stride = gridDim.x * blockDim.x;
  for (; i < n8; i += stride) {
    const float4* p = (const float4*)src + (size_t)i * 2;
    float4 a = p[0], b = p[1];
    bf16 tmp[8];
    tmp[0] = __float2bfloat16(a.x); tmp[1] = __float2bfloat16(a.y);
    tmp[2] = __float2bfloat16(a.z); tmp[3] = __float2bfloat16(a.w);
    tmp[4] = __float2bfloat16(b.x); tmp[5] = __float2bfloat16(b.y);
    tmp[6] = __float2bfloat16(b.z); tmp[7] = __float2bfloat16(b.w);
    *(short8*)(dst + (size_t)i * 8) = *(short8*)tmp;
  }
}

// ---- fused 4-weight fp32->bf16 convert ----
__global__ __launch_bounds__(256) void k_cvtw(
    const float* __restrict__ w0, const float* __restrict__ w1,
    const float* __restrict__ w2, const float* __restrict__ w3,
    bf16* __restrict__ d0, bf16* __restrict__ d1,
    bf16* __restrict__ d2, bf16* __restrict__ d3) {
  int gi = blockIdx.x * 256 + threadIdx.x;   // [0, 524288)
  int m = gi >> 17;
  int i = gi & 131071;
  const float* src = (m == 0) ? w0 : (m == 1) ? w1 : (m == 2) ? w2 : w3;
  bf16* dst = (m == 0) ? d0 : (m == 1) ? d1 : (m == 2) ? d2 : d3;
  const float4* p = (const float4*)src + (size_t)i * 2;
  float4 a = p[0], b = p[1];
  bf16 tmp[8];
  tmp[0] = __float2bfloat16(a.x); tmp[1] = __float2bfloat16(a.y);
  tmp[2] = __float2bfloat16(a.z); tmp[3] = __float2bfloat16(a.w);
  tmp[4] = __float2bfloat16(b.x); tmp[5] = __float2bfloat16(b.y);
  tmp[6] = __float2bfloat16(b.z); tmp[7] = __float2bfloat16(b.w);
  *(short8*)(dst + (size_t)i * 8) = *(short8*)tmp;
}

// ======== GEMM body A: 128x256 tile, BK=32, occupancy-first (qkv) =========

#define GEMM_BODY128(...)                                                      \
  const int Kd = 1024;                                                         \
  const int nk = 32;                                                           \
  __shared__ bf16 As[2][128 * 32];                                             \
  __shared__ bf16 Bs[2][256 * 32];                                             \
  int tid = threadIdx.x;                                                       \
  int lane = tid & 63, wid = tid >> 6;                                         \
  int l15 = lane & 15, hi = lane >> 4;                                         \
  int wm = wid >> 2, wn = wid & 3;                                             \
  f32x4 acc[4][4];                                                             \
  _Pragma("unroll") for (int i = 0; i < 4; i++)                                \
      _Pragma("unroll") for (int j = 0; j < 4; j++)                            \
          acc[i][j] = (f32x4){0.f, 0.f, 0.f, 0.f};                             \
  auto stage = [&](int slot, int kk) {                                         \
    const bf16* ab = Abase + kk * 32;                                          \
    const bf16* bb = Bbase + kk * 32;                                          \
    {                                                                          \
      int p = tid;                                                             \
      int row = p >> 2;                                                        \
      int u = (p & 3) ^ ((row >> 1) & 3);                                      \
      gl16(ab + (size_t)row * Kd + u * 8, (char*)(&As[slot][0]) + p * 16);     \
    }                                                                          \
    _Pragma("unroll") for (int pass = 0; pass < 2; pass++) {                   \
      int p = pass * 512 + tid;                                                \
      int row = p >> 2;                                                        \
      int u = (p & 3) ^ ((row >> 1) & 3);                                      \
      gl16(bb + (size_t)row * Kd + u * 8, (char*)(&Bs[slot][0]) + p * 16);     \
    }                                                                          \
  };                                                                           \
  stage(0, 0);                                                                 \
  asm volatile("s_waitcnt vmcnt(0)" ::: "memory");                             \
  SCHED0; __builtin_amdgcn_s_barrier(); SCHED0;                                \
  int sw = ((l15 >> 1) & 3) << 4;                                              \
  int arow = wm * 64 + l15;                                                    \
  int brow = wn * 64 + l15;                                                    \
  _Pragma("unroll 2") for (int t = 0; t < nk; ++t) {                           \
    int s = t & 1;                                                             \
    const char* Ab = (const char*)(&As[s][0]);                                 \
    const char* Bb = (const char*)(&Bs[s][0]);                                 \
    if (t + 1 < nk) stage(s ^ 1, t + 1);                                       \
    short8 af[4], bfr[4];                                                      \
    _Pragma("unroll") for (int mf = 0; mf < 4; mf++)                           \
        af[mf] = *(const short8*)(Ab +                                         \
            (((arow + mf * 16) * 64 + hi * 16) ^ sw));                         \
    _Pragma("unroll") for (int nf = 0; nf < 4; nf++)                           \
        bfr[nf] = *(const short8*)(Bb +                                        \
            (((brow + nf * 16) * 64 + hi * 16) ^ sw));                         \
    SCHED0;                                                                    \
    __builtin_amdgcn_s_setprio(1);                                             \
    _Pragma("unroll") for (int mf = 0; mf < 4; mf++)                           \
        _Pragma("unroll") for (int nf = 0; nf < 4; nf++)                       \
            acc[mf][nf] = __builtin_amdgcn_mfma_f32_16x16x32_bf16(             \
                af[mf], bfr[nf], acc[mf][nf], 0, 0, 0);                        \
    __builtin_amdgcn_s_setprio(0);                                             \
    SCHED0;                                                                    \
    if (t + 1 < nk) {                                                          \
      asm volatile("s_waitcnt vmcnt(0)" ::: "memory");                         \
      SCHED0; __builtin_amdgcn_s_barrier(); SCHED0;                            \
    }                                                                          \
  }                                                                            \
  __VA_ARGS__

// ======== GEMM body B: 256x256 tile, BK=32, 4-slot ring (out_gemm) ========

#define GEMM_BODY256(...)                                                      \
  const int Kd = 1024;                                                         \
  const int nk = 32;                                                           \
  __shared__ bf16 As[4][256 * 32];                                             \
  __shared__ bf16 Bs[4][256 * 32];                                             \
  int tid = threadIdx.x;                                                       \
  int lane = tid & 63, wid = tid >> 6;                                         \
  int l15 = lane & 15, hi = lane >> 4;                                         \
  int wm = wid >> 2, wn = wid & 3;                                             \
  f32x4 acc[8][4];                                                             \
  _Pragma("unroll") for (int i = 0; i < 8; i++)                                \
      _Pragma("unroll") for (int j = 0; j < 4; j++)                            \
          acc[i][j] = (f32x4){0.f, 0.f, 0.f, 0.f};                             \
  auto stageA = [&](int slot, int kk) {                                        \
    const bf16* ab = Abase + kk * 32;                                          \
    _Pragma("unroll") for (int pass = 0; pass < 2; pass++) {                   \
      int p = pass * 512 + tid;                                                \
      int row = p >> 2;                                                        \
      int u = (p & 3) ^ ((row >> 1) & 3);                                      \
      gl16(ab + (size_t)row * Kd + u * 8, (char*)(&As[slot][0]) + p * 16);     \
    }                                                                          \
  };                                                                           \
  auto stageB = [&](int slot, int kk) {                                        \
    const bf16* bb = Bbase + kk * 32;                                          \
    _Pragma("unroll") for (int pass = 0; pass < 2; pass++) {                   \
      int p = pass * 512 + tid;                                                \
      int row = p >> 2;                                                        \
      int u = (p & 3) ^ ((row >> 1) & 3);                                      \
      gl16(bb + (size_t)row * Kd + u * 8, (char*)(&Bs[slot][0]) + p * 16);     \
    }                                                                          \
  };                                                                           \
  stageA(0, 0); stageB(0, 0);                                                  \
  stageA(1, 1); stageB(1, 1);                                                  \
  stageA(2, 2); stageB(2, 2);                                                  \
  asm volatile("s_waitcnt vmcnt(8)" ::: "memory");                             \
  SCHED0; __builtin_amdgcn_s_barrier(); SCHED0;                                \
  int sw = ((l15 >> 1) & 3) << 4;                                              \
  int arow = wm * 128 + l15;                                                   \
  int brow = wn * 64 + l15;                                                    \
  short8 ax[4], ahi[4], bcur[4], axn[4], bn[4];                                \
  _Pragma("unroll") for (int mf = 0; mf < 4; mf++)                             \
      ax[mf] = *(const short8*)((const char*)(&As[0][0]) +                     \
                                (((arow + mf * 16) * 64 + hi * 16) ^ sw));     \
  _Pragma("unroll") for (int nf = 0; nf < 4; nf++)                             \
      bcur[nf] = *(const short8*)((const char*)(&Bs[0][0]) +                   \
                                  (((brow + nf * 16) * 64 + hi * 16) ^ sw));   \
  _Pragma("unroll 2") for (int t = 0; t < nk; ++t) {                           \
    int s = t & 3, sn = (t + 1) & 3;                                           \
    const char* Ab = (const char*)(&As[s][0]);                                 \
    _Pragma("unroll") for (int mf = 0; mf < 4; mf++)                           \
        ahi[mf] = *(const short8*)(Ab +                                        \
            (((arow + 64 + mf * 16) * 64 + hi * 16) ^ sw));                    \
    if (t + 3 < nk) stageA((t + 3) & 3, t + 3);                                \
    SCHED0;                                                                    \
    __builtin_amdgcn_s_setprio(1);                                             \
    _Pragma("unroll") for (int mf = 0; mf < 4; mf++)                           \
        _Pragma("unroll") for (int nf = 0; nf < 4; nf++)                       \
            acc[mf][nf] = __builtin_amdgcn_mfma_f32_16x16x32_bf16(             \
                ax[mf], bcur[nf], acc[mf][nf], 0, 0, 0);                       \
    __builtin_amdgcn_s_setprio(0);                                             \
    SCHED0;                                                                    \
    if (t + 1 < nk) {                                                          \
      if (t + 3 < nk)      asm volatile("s_waitcnt vmcnt(6)" ::: "memory");    \
      else if (t + 2 < nk) asm volatile("s_waitcnt vmcnt(4)" ::: "memory");    \
      else                 asm volatile("s_waitcnt vmcnt(0)" ::: "memory");    \
      SCHED0; __builtin_amdgcn_s_barrier(); SCHED0;                            \
      if (t + 3 < nk) stageB((t + 3) & 3, t + 3);                              \
      const char* AbN = (const char*)(&As[sn][0]);                             \
      const char* BbN = (const char*)(&Bs[sn][0]);                             \
      _Pragma("unroll") for (int mf = 0; mf < 4; mf++)                         \
          axn[mf] = *(const short8*)(AbN +                                     \
              (((arow + mf * 16) * 64 + hi * 16) ^ sw));                       \
      _Pragma("unroll") for (int nf = 0; nf < 4; nf++)                         \
          bn[nf] = *(const short8*)(BbN +                                      \
              (((brow + nf * 16) * 64 + hi * 16) ^ sw));                       \
      SCHED0;                                                                  \
    }                                                                          \
    __builtin_amdgcn_s_setprio(1);                                             \
    _Pragma("unroll") for (int mf = 0; mf < 4; mf++)                           \
        _Pragma("unroll") for (int nf = 0; nf < 4; nf++)                       \
            acc[mf + 4][nf] = __builtin_amdgcn_mfma_f32_16x16x32_bf16(         \
                ahi[mf], bcur[nf], acc[mf + 4][nf], 0, 0, 0);                  \
    __builtin_amdgcn_s_setprio(0);                                             \
    SCHED0;                                                                    \
    if (t + 1 < nk) {                                                          \
      __builtin_amdgcn_s_barrier(); SCHED0;                                    \
      _Pragma("unroll") for (int i = 0; i < 4; i++) {                          \
        ax[i] = axn[i]; bcur[i] = bn[i];                                       \
      }                                                                        \
    }                                                                          \
  }                                                                            \
  __VA_ARGS__

// QKV GEMM. wsel 0,1 (Q,K): A=X rows=tokens, B=W rows=channels -> C=X W^T.
// wsel 2 (V): operands swapped -> C[ch][tok] = V^T directly (no vtrans).
__global__ __launch_bounds__(512, 4) void k_qkv_gemm(
    const bf16* __restrict__ X, const bf16* __restrict__ Wq,
    const bf16* __restrict__ Wk, const bf16* __restrict__ Wv,
    bf16* __restrict__ Q, bf16* __restrict__ K, bf16* __restrict__ VT) {
  int bid = blockIdx.x;
  int wsel = bid >> 9;       // 0..2 (512 blocks each)
  int rem = bid & 511;
  int mt, nt;
  const bf16 *Abase, *Bbase;
  if (wsel < 2) {
    mt = rem & 127;          // token tile (128)
    nt = rem >> 7;           // channel tile (256)
    Abase = X + (size_t)mt * 128 * 1024;
    Bbase = ((wsel == 0) ? Wq : Wk) + (size_t)nt * 256 * 1024;
  } else {
    mt = rem & 7;            // channel tile (128): 1024/128 = 8
    nt = rem >> 3;           // token tile (256): 16384/256 = 64
    Abase = Wv + (size_t)mt * 128 * 1024;
    Bbase = X + (size_t)nt * 256 * 1024;
  }
  GEMM_BODY128({
    if (wsel < 2) {
      bf16* Dst = (wsel == 0) ? Q : K;
      _Pragma("unroll") for (int mf = 0; mf < 4; mf++) {
        _Pragma("unroll") for (int r = 0; r < 4; r++) {
          int row = mt * 128 + wm * 64 + mf * 16 + hi * 4 + r;  // token
          int b = row >> 13;
          int tok = row & 8191;
          _Pragma("unroll") for (int nf = 0; nf < 4; nf++) {
            int col = nt * 256 + wn * 64 + nf * 16 + l15;        // channel
            int h = col >> 6;
            int d = col & 63;
            Dst[((size_t)(b * 16 + h) * 8192 + tok) * 64 + d] =
                __float2bfloat16(acc[mf][nf][r]);
          }
        }
      }
    } else {
      _Pragma("unroll") for (int mf = 0; mf < 4; mf++) {
        _Pragma("unroll") for (int r = 0; r < 4; r++) {
          int ch = mt * 128 + wm * 64 + mf * 16 + hi * 4 + r;    // channel
          int h = ch >> 6;
          int d = ch & 63;
          _Pragma("unroll") for (int nf = 0; nf < 4; nf++) {
            int tok = nt * 256 + wn * 64 + nf * 16 + l15;        // token
            int b = tok >> 13;
            int t2 = tok & 8191;
            VT[((size_t)(b * 16 + h) * 64 + d) * 8192 + t2] =
                __float2bfloat16(acc[mf][nf][r]);
          }
        }
      }
    }
  })
}

__global__ __launch_bounds__(512, 2) void k_out_gemm(
    const bf16* __restrict__ A, const bf16* __restrict__ Wo,
    float* __restrict__ Out) {
  int bid = blockIdx.x;
  int mt = bid & 63;
  int nt = bid >> 6;
  const bf16* Abase = A + (size_t)mt * 256 * 1024;
  const bf16* Bbase = Wo + (size_t)nt * 256 * 1024;
  GEMM_BODY256({
    _Pragma("unroll") for (int mf = 0; mf < 8; mf++) {
      _Pragma("unroll") for (int r = 0; r < 4; r++) {
        int row = mt * 256 + wm * 128 + mf * 16 + hi * 4 + r;
        _Pragma("unroll") for (int nf = 0; nf < 4; nf++) {
          int col = nt * 256 + wn * 64 + nf * 16 + l15;
          Out[(size_t)row * 1024 + col] = acc[mf][nf][r];
        }
      }
    }
  })
}

// ---------------- sliding-window attention (Q-tile 128, 8 waves) -----------
// R17-measured staging (2-slot, stage-at-top, drain barrier at bottom) +
// STATIC-MAX softmax. NEW: P distributed to MFMA-A fragments via register
// SHUFFLES (no P LDS buffer -> 32KB LDS -> 4 blocks/CU).
// Derivation: lane(l15,hi) holds pv[ks][r] = P[l15][ks*16+hi*4+r]; A-frag
// needs P[l15][js*32+hi*8+e]. For word k (e=2k,2k+1): src lane =
// ((hi&1)*2+(k>>1))*16 + l15; slot ks = js*2+(hi>>1); word = k&1. ks depends
// on TARGET lane -> shuffle both candidates, select by hi>>1.
__global__ __launch_bounds__(512) void k_attn(
    const bf16* __restrict__ Q, const bf16* __restrict__ K,
    const bf16* __restrict__ VT, bf16* __restrict__ ATT) {
  const int T = 8192;
  __shared__ bf16 Ks[2][64 * 64];
  __shared__ bf16 Vs[2][64 * 64];  // V^T chunk: [d][j]
  int bid = blockIdx.x;
  int qt = bid & 63;
  int bh = bid >> 6;  // 0..31
  int b = bh >> 4, h = bh & 15;
  int tid = threadIdx.x;
  int lane = tid & 63, wid = tid >> 6;
  int l15 = lane & 15, hi = lane >> 4;
  int q0 = qt * 128;
  int qw = q0 + wid * 16;

  short8 bq[2];
  const bf16* qp = Q + ((size_t)bh * T + qw + l15) * 64 + hi * 8;
  bq[0] = *(const short8*)qp;
  bq[1] = *(const short8*)(qp + 32);

  const bf16* Kbh = K + (size_t)bh * T * 64;
  const bf16* Vbh = VT + (size_t)bh * 64 * T;

  auto stage = [&](int bb, int c0) {
    int p = tid;  // 512 threads x 16B = 8KB per buffer
    int row = p >> 3;
    int u = (p & 7) ^ (row & 7);
    gl16(Kbh + ((size_t)(c0 + row)) * 64 + u * 8, (char*)(&Ks[bb][0]) + p * 16);
    gl16(Vbh + (size_t)row * T + c0 + u * 8, (char*)(&Vs[bb][0]) + p * 16);
  };

  int cstart = q0 - 512; if (cstart < 0) cstart = 0;
  int nch = (q0 + 128 - cstart) >> 6;

  f32x4 oacc[4];
#pragma unroll
  for (int c = 0; c < 4; c++) oacc[c] = (f32x4){0.f, 0.f, 0.f, 0.f};
  float ssum = 0.f;

  stage(0, cstart);
  __syncthreads();
  int buf = 0;
  for (int ci = 0; ci < nch; ci++) {
    int c0 = cstart + (ci << 6);
    if (ci + 1 < nch) stage(buf ^ 1, c0 + 64);
    f32x4 sacc[4];
#pragma unroll
    for (int ks = 0; ks < 4; ks++) sacc[ks] = (f32x4){0.f, 0.f, 0.f, 0.f};
#pragma unroll
    for (int dh = 0; dh < 2; dh++) {
#pragma unroll
      for (int ks = 0; ks < 4; ks++) {
        int krow = ks * 16 + l15;
        int boff = ((krow * 64 + dh * 32 + hi * 8) * 2) ^ ((krow & 7) << 4);
        short8 ak = *(const short8*)((const char*)(&Ks[buf][0]) + boff);
        sacc[ks] = __builtin_amdgcn_mfma_f32_16x16x32_bf16(ak, bq[dh], sacc[ks], 0, 0, 0);
      }
    }
    // static-max softmax: p = exp(s*0.125 - 12), masked to window
    float pv[4][4];
    float psum = 0.f;
    bool fullok = (c0 + 63 <= qw) && (c0 + 512 >= qw + 16);  // wave-uniform
    if (fullok) {
#pragma unroll
      for (int ks = 0; ks < 4; ks++)
#pragma unroll
        for (int r = 0; r < 4; r++) {
          float p = __expf(fmaf(sacc[ks][r], 0.125f, -12.0f));
          pv[ks][r] = p;
          psum += p;
        }
    } else {
      int qg = qw + l15;
#pragma unroll
      for (int ks = 0; ks < 4; ks++)
#pragma unroll
        for (int r = 0; r < 4; r++) {
          int jg = c0 + ks * 16 + hi * 4 + r;
          float p = __expf(fmaf(sacc[ks][r], 0.125f, -12.0f));
          p = ((jg <= qg) && (jg > qg - 512)) ? p : 0.f;
          pv[ks][r] = p;
          psum += p;
        }
    }
    psum += __shfl_xor(psum, 16);
    psum += __shfl_xor(psum, 32);
    ssum += psum;
    // pack P rows to bf16 words: w0/w1 per ks
    unsigned int w0[4], w1[4];
#pragma unroll
    for (int ks = 0; ks < 4; ks++) {
      w0[ks] = (unsigned)bfbits(pv[ks][0]) | ((unsigned)bfbits(pv[ks][1]) << 16);
      w1[ks] = (unsigned)bfbits(pv[ks][2]) | ((unsigned)bfbits(pv[ks][3]) << 16);
    }
    int sel = hi >> 1;
    int sl_lo = ((hi & 1) * 2) * 16 + l15;       // src lane for k=0,1
    int sl_hi = ((hi & 1) * 2 + 1) * 16 + l15;   // src lane for k=2,3
#pragma unroll
    for (int js = 0; js < 2; js++) {
      int ksA = js * 2, ksB = js * 2 + 1;
      unsigned int wrd[4];
      {
        unsigned int a0 = __shfl(w0[ksA], sl_lo), b0 = __shfl(w0[ksB], sl_lo);
        unsigned int a1 = __shfl(w1[ksA], sl_lo), b1 = __shfl(w1[ksB], sl_lo);
        unsigned int a2 = __shfl(w0[ksA], sl_hi), b2 = __shfl(w0[ksB], sl_hi);
        unsigned int a3 = __shfl(w1[ksA], sl_hi), b3 = __shfl(w1[ksB], sl_hi);
        wrd[0] = sel ? b0 : a0;
        wrd[1] = sel ? b1 : a1;
        wrd[2] = sel ? b2 : a2;
        wrd[3] = sel ? b3 : a3;
      }
      short8 ap;
      unsigned int* pw = (unsigned int*)&ap;
      pw[0] = wrd[0]; pw[1] = wrd[1]; pw[2] = wrd[2]; pw[3] = wrd[3];
#pragma unroll
      for (int c = 0; c < 4; c++) {
        int vrow = c * 16 + l15;
        int boff = ((vrow * 64 + js * 32 + hi * 8) * 2) ^ ((vrow & 7) << 4);
        short8 bv = *(const short8*)((const char*)(&Vs[buf][0]) + boff);
        oacc[c] = __builtin_amdgcn_mfma_f32_16x16x32_bf16(ap, bv, oacc[c], 0, 0, 0);
      }
    }
    __syncthreads();
    buf ^= 1;
  }
  float inv = 1.f / ssum;
#pragma unroll
  for (int r = 0; r < 4; r++) {
    float f = __shfl(inv, hi * 4 + r);
    int tok = qw + hi * 4 + r;
    bf16* dst = ATT + ((size_t)b * 8192 + tok) * 1024 + h * 64;
#pragma unroll
    for (int c = 0; c < 4; c++)
      dst[c * 16 + l15] = __float2bfloat16(oacc[c][r] * f);
  }
}

extern "C" void kernel_launch(void* const* d_in, const int* in_sizes, int n_in,
                              void* d_out, int out_size, void* d_ws, size_t ws_size,
                              hipStream_t stream) {
  const float* x  = (const float*)d_in[0];
  const float* wq = (const float*)d_in[1];
  const float* wk = (const float*)d_in[2];
  const float* wv = (const float*)d_in[3];
  const float* wo = (const float*)d_in[4];
  float* out = (float*)d_out;

  char* ws = (char*)d_ws;
  const size_t SZ_X = (size_t)16384 * 1024 * 2;  // 32 MB bf16
  const size_t SZ_W = (size_t)1024 * 1024 * 2;   // 2 MB bf16
  size_t off = 0;
  bf16* xb  = (bf16*)(ws + off); off += SZ_X;
  bf16* wqb = (bf16*)(ws + off); off += SZ_W;
  bf16* wkb = (bf16*)(ws + off); off += SZ_W;
  bf16* wvb = (bf16*)(ws + off); off += SZ_W;
  bf16* wob = (bf16*)(ws + off); off += SZ_W;
  bf16* qb  = (bf16*)(ws + off); off += SZ_X;
  bf16* kb  = (bf16*)(ws + off); off += SZ_X;
  bf16* vtb = (bf16*)(ws + off); off += SZ_X;
  bf16* att = xb;  // alias: x_bf16 dead after QKV GEMM

  k_cvt<<<2048, 256, 0, stream>>>(x, xb, 16384 * 1024 / 8);
  k_cvtw<<<2048, 256, 0, stream>>>(wq, wk, wv, wo, wqb, wkb, wvb, wob);
  k_qkv_gemm<<<1536, 512, 0, stream>>>(xb, wqb, wkb, wvb, qb, kb, vtb);
  k_attn<<<2048, 512, 0, stream>>>(qb, kb, vtb, att);
  k_out_gemm<<<256, 512, 0, stream>>>(att, wob, out);
}

// Round 20
// 281.817 us; speedup vs baseline: 1.0095x; 1.0095x over previous
//
#include <hip/hip_runtime.h>
#include <hip/hip_bf16.h>
#include <stdint.h>

typedef __attribute__((ext_vector_type(8))) short short8;
typedef __attribute__((ext_vector_type(4))) float f32x4;
typedef __hip_bfloat16 bf16;

#define AS1 __attribute__((address_space(1)))
#define AS3 __attribute__((address_space(3)))

__device__ __forceinline__ void gl16(const void* g, void* l) {
  __builtin_amdgcn_global_load_lds((const AS1 unsigned int*)g,
                                   (AS3 unsigned int*)l, 16, 0, 0);
}

__device__ __forceinline__ unsigned short bfbits(float x) {
  union { bf16 b; unsigned short u; } c; c.b = __float2bfloat16(x); return c.u;
}

#define SCHED0 __builtin_amdgcn_sched_barrier(0)

// ---------------- fp32 -> bf16 convert (vectorized) ----------------
__global__ __launch_bounds__(256) void k_cvt(const float* __restrict__ src,
                                             bf16* __restrict__ dst, int n8) {
  int i = blockIdx.x * blockDim.x + threadIdx.x;
  int stride = gridDim.x * blockDim.x;
  for (; i < n8; i += stride) {
    const float4* p = (const float4*)src + (size_t)i * 2;
    float4 a = p[0], b = p[1];
    bf16 tmp[8];
    tmp[0] = __float2bfloat16(a.x); tmp[1] = __float2bfloat16(a.y);
    tmp[2] = __float2bfloat16(a.z); tmp[3] = __float2bfloat16(a.w);
    tmp[4] = __float2bfloat16(b.x); tmp[5] = __float2bfloat16(b.y);
    tmp[6] = __float2bfloat16(b.z); tmp[7] = __float2bfloat16(b.w);
    *(short8*)(dst + (size_t)i * 8) = *(short8*)tmp;
  }
}

// ---- fused 4-weight fp32->bf16 convert ----
__global__ __launch_bounds__(256) void k_cvtw(
    const float* __restrict__ w0, const float* __restrict__ w1,
    const float* __restrict__ w2, const float* __restrict__ w3,
    bf16* __restrict__ d0, bf16* __restrict__ d1,
    bf16* __restrict__ d2, bf16* __restrict__ d3) {
  int gi = blockIdx.x * 256 + threadIdx.x;   // [0, 524288)
  int m = gi >> 17;
  int i = gi & 131071;
  const float* src = (m == 0) ? w0 : (m == 1) ? w1 : (m == 2) ? w2 : w3;
  bf16* dst = (m == 0) ? d0 : (m == 1) ? d1 : (m == 2) ? d2 : d3;
  const float4* p = (const float4*)src + (size_t)i * 2;
  float4 a = p[0], b = p[1];
  bf16 tmp[8];
  tmp[0] = __float2bfloat16(a.x); tmp[1] = __float2bfloat16(a.y);
  tmp[2] = __float2bfloat16(a.z); tmp[3] = __float2bfloat16(a.w);
  tmp[4] = __float2bfloat16(b.x); tmp[5] = __float2bfloat16(b.y);
  tmp[6] = __float2bfloat16(b.z); tmp[7] = __float2bfloat16(b.w);
  *(short8*)(dst + (size_t)i * 8) = *(short8*)tmp;
}

// ======== GEMM body A: 128x256 tile, BK=32, occupancy-first (qkv) =========

#define GEMM_BODY128(...)                                                      \
  const int Kd = 1024;                                                         \
  const int nk = 32;                                                           \
  __shared__ bf16 As[2][128 * 32];                                             \
  __shared__ bf16 Bs[2][256 * 32];                                             \
  int tid = threadIdx.x;                                                       \
  int lane = tid & 63, wid = tid >> 6;                                         \
  int l15 = lane & 15, hi = lane >> 4;                                         \
  int wm = wid >> 2, wn = wid & 3;                                             \
  f32x4 acc[4][4];                                                             \
  _Pragma("unroll") for (int i = 0; i < 4; i++)                                \
      _Pragma("unroll") for (int j = 0; j < 4; j++)                            \
          acc[i][j] = (f32x4){0.f, 0.f, 0.f, 0.f};                             \
  auto stage = [&](int slot, int kk) {                                         \
    const bf16* ab = Abase + kk * 32;                                          \
    const bf16* bb = Bbase + kk * 32;                                          \
    {                                                                          \
      int p = tid;                                                             \
      int row = p >> 2;                                                        \
      int u = (p & 3) ^ ((row >> 1) & 3);                                      \
      gl16(ab + (size_t)row * Kd + u * 8, (char*)(&As[slot][0]) + p * 16);     \
    }                                                                          \
    _Pragma("unroll") for (int pass = 0; pass < 2; pass++) {                   \
      int p = pass * 512 + tid;                                                \
      int row = p >> 2;                                                        \
      int u = (p & 3) ^ ((row >> 1) & 3);                                      \
      gl16(bb + (size_t)row * Kd + u * 8, (char*)(&Bs[slot][0]) + p * 16);     \
    }                                                                          \
  };                                                                           \
  stage(0, 0);                                                                 \
  asm volatile("s_waitcnt vmcnt(0)" ::: "memory");                             \
  SCHED0; __builtin_amdgcn_s_barrier(); SCHED0;                                \
  int sw = ((l15 >> 1) & 3) << 4;                                              \
  int arow = wm * 64 + l15;                                                    \
  int brow = wn * 64 + l15;                                                    \
  _Pragma("unroll 2") for (int t = 0; t < nk; ++t) {                           \
    int s = t & 1;                                                             \
    const char* Ab = (const char*)(&As[s][0]);                                 \
    const char* Bb = (const char*)(&Bs[s][0]);                                 \
    if (t + 1 < nk) stage(s ^ 1, t + 1);                                       \
    short8 af[4], bfr[4];                                                      \
    _Pragma("unroll") for (int mf = 0; mf < 4; mf++)                           \
        af[mf] = *(const short8*)(Ab +                                         \
            (((arow + mf * 16) * 64 + hi * 16) ^ sw));                         \
    _Pragma("unroll") for (int nf = 0; nf < 4; nf++)                           \
        bfr[nf] = *(const short8*)(Bb +                                        \
            (((brow + nf * 16) * 64 + hi * 16) ^ sw));                         \
    SCHED0;                                                                    \
    __builtin_amdgcn_s_setprio(1);                                             \
    _Pragma("unroll") for (int mf = 0; mf < 4; mf++)                           \
        _Pragma("unroll") for (int nf = 0; nf < 4; nf++)                       \
            acc[mf][nf] = __builtin_amdgcn_mfma_f32_16x16x32_bf16(             \
                af[mf], bfr[nf], acc[mf][nf], 0, 0, 0);                        \
    __builtin_amdgcn_s_setprio(0);                                             \
    SCHED0;                                                                    \
    if (t + 1 < nk) {                                                          \
      asm volatile("s_waitcnt vmcnt(0)" ::: "memory");                         \
      SCHED0; __builtin_amdgcn_s_barrier(); SCHED0;                            \
    }                                                                          \
  }                                                                            \
  __VA_ARGS__

// ======== GEMM body B: 256x256 tile, BK=32, 4-slot ring (out_gemm) ========

#define GEMM_BODY256(...)                                                      \
  const int Kd = 1024;                                                         \
  const int nk = 32;                                                           \
  __shared__ bf16 As[4][256 * 32];                                             \
  __shared__ bf16 Bs[4][256 * 32];                                             \
  int tid = threadIdx.x;                                                       \
  int lane = tid & 63, wid = tid >> 6;                                         \
  int l15 = lane & 15, hi = lane >> 4;                                         \
  int wm = wid >> 2, wn = wid & 3;                                             \
  f32x4 acc[8][4];                                                             \
  _Pragma("unroll") for (int i = 0; i < 8; i++)                                \
      _Pragma("unroll") for (int j = 0; j < 4; j++)                            \
          acc[i][j] = (f32x4){0.f, 0.f, 0.f, 0.f};                             \
  auto stageA = [&](int slot, int kk) {                                        \
    const bf16* ab = Abase + kk * 32;                                          \
    _Pragma("unroll") for (int pass = 0; pass < 2; pass++) {                   \
      int p = pass * 512 + tid;                                                \
      int row = p >> 2;                                                        \
      int u = (p & 3) ^ ((row >> 1) & 3);                                      \
      gl16(ab + (size_t)row * Kd + u * 8, (char*)(&As[slot][0]) + p * 16);     \
    }                                                                          \
  };                                                                           \
  auto stageB = [&](int slot, int kk) {                                        \
    const bf16* bb = Bbase + kk * 32;                                          \
    _Pragma("unroll") for (int pass = 0; pass < 2; pass++) {                   \
      int p = pass * 512 + tid;                                                \
      int row = p >> 2;                                                        \
      int u = (p & 3) ^ ((row >> 1) & 3);                                      \
      gl16(bb + (size_t)row * Kd + u * 8, (char*)(&Bs[slot][0]) + p * 16);     \
    }                                                                          \
  };                                                                           \
  stageA(0, 0); stageB(0, 0);                                                  \
  stageA(1, 1); stageB(1, 1);                                                  \
  stageA(2, 2); stageB(2, 2);                                                  \
  asm volatile("s_waitcnt vmcnt(8)" ::: "memory");                             \
  SCHED0; __builtin_amdgcn_s_barrier(); SCHED0;                                \
  int sw = ((l15 >> 1) & 3) << 4;                                              \
  int arow = wm * 128 + l15;                                                   \
  int brow = wn * 64 + l15;                                                    \
  short8 ax[4], ahi[4], bcur[4], axn[4], bn[4];                                \
  _Pragma("unroll") for (int mf = 0; mf < 4; mf++)                             \
      ax[mf] = *(const short8*)((const char*)(&As[0][0]) +                     \
                                (((arow + mf * 16) * 64 + hi * 16) ^ sw));     \
  _Pragma("unroll") for (int nf = 0; nf < 4; nf++)                             \
      bcur[nf] = *(const short8*)((const char*)(&Bs[0][0]) +                   \
                                  (((brow + nf * 16) * 64 + hi * 16) ^ sw));   \
  _Pragma("unroll 2") for (int t = 0; t < nk; ++t) {                           \
    int s = t & 3, sn = (t + 1) & 3;                                           \
    const char* Ab = (const char*)(&As[s][0]);                                 \
    _Pragma("unroll") for (int mf = 0; mf < 4; mf++)                           \
        ahi[mf] = *(const short8*)(Ab +                                        \
            (((arow + 64 + mf * 16) * 64 + hi * 16) ^ sw));                    \
    if (t + 3 < nk) stageA((t + 3) & 3, t + 3);                                \
    SCHED0;                                                                    \
    __builtin_amdgcn_s_setprio(1);                                             \
    _Pragma("unroll") for (int mf = 0; mf < 4; mf++)                           \
        _Pragma("unroll") for (int nf = 0; nf < 4; nf++)                       \
            acc[mf][nf] = __builtin_amdgcn_mfma_f32_16x16x32_bf16(             \
                ax[mf], bcur[nf], acc[mf][nf], 0, 0, 0);                       \
    __builtin_amdgcn_s_setprio(0);                                             \
    SCHED0;                                                                    \
    if (t + 1 < nk) {                                                          \
      if (t + 3 < nk)      asm volatile("s_waitcnt vmcnt(6)" ::: "memory");    \
      else if (t + 2 < nk) asm volatile("s_waitcnt vmcnt(4)" ::: "memory");    \
      else                 asm volatile("s_waitcnt vmcnt(0)" ::: "memory");    \
      SCHED0; __builtin_amdgcn_s_barrier(); SCHED0;                            \
      if (t + 3 < nk) stageB((t + 3) & 3, t + 3);                              \
      const char* AbN = (const char*)(&As[sn][0]);                             \
      const char* BbN = (const char*)(&Bs[sn][0]);                             \
      _Pragma("unroll") for (int mf = 0; mf < 4; mf++)                         \
          axn[mf] = *(const short8*)(AbN +                                     \
              (((arow + mf * 16) * 64 + hi * 16) ^ sw));                       \
      _Pragma("unroll") for (int nf = 0; nf < 4; nf++)                         \
          bn[nf] = *(const short8*)(BbN +                                      \
              (((brow + nf * 16) * 64 + hi * 16) ^ sw));                       \
      SCHED0;                                                                  \
    }                                                                          \
    __builtin_amdgcn_s_setprio(1);                                             \
    _Pragma("unroll") for (int mf = 0; mf < 4; mf++)                           \
        _Pragma("unroll") for (int nf = 0; nf < 4; nf++)                       \
            acc[mf + 4][nf] = __builtin_amdgcn_mfma_f32_16x16x32_bf16(         \
                ahi[mf], bcur[nf], acc[mf + 4][nf], 0, 0, 0);                  \
    __builtin_amdgcn_s_setprio(0);                                             \
    SCHED0;                                                                    \
    if (t + 1 < nk) {                                                          \
      __builtin_amdgcn_s_barrier(); SCHED0;                                    \
      _Pragma("unroll") for (int i = 0; i < 4; i++) {                          \
        ax[i] = axn[i]; bcur[i] = bn[i];                                       \
      }                                                                        \
    }                                                                          \
  }                                                                            \
  __VA_ARGS__

// QKV GEMM. wsel 0,1 (Q,K): A=X rows=tokens, B=W rows=channels -> C=X W^T.
// wsel 2 (V): operands swapped -> C[ch][tok] = V^T directly (no vtrans).
__global__ __launch_bounds__(512, 4) void k_qkv_gemm(
    const bf16* __restrict__ X, const bf16* __restrict__ Wq,
    const bf16* __restrict__ Wk, const bf16* __restrict__ Wv,
    bf16* __restrict__ Q, bf16* __restrict__ K, bf16* __restrict__ VT) {
  int bid = blockIdx.x;
  int wsel = bid >> 9;       // 0..2 (512 blocks each)
  int rem = bid & 511;
  int mt, nt;
  const bf16 *Abase, *Bbase;
  if (wsel < 2) {
    mt = rem & 127;          // token tile (128)
    nt = rem >> 7;           // channel tile (256)
    Abase = X + (size_t)mt * 128 * 1024;
    Bbase = ((wsel == 0) ? Wq : Wk) + (size_t)nt * 256 * 1024;
  } else {
    mt = rem & 7;            // channel tile (128): 1024/128 = 8
    nt = rem >> 3;           // token tile (256): 16384/256 = 64
    Abase = Wv + (size_t)mt * 128 * 1024;
    Bbase = X + (size_t)nt * 256 * 1024;
  }
  GEMM_BODY128({
    if (wsel < 2) {
      bf16* Dst = (wsel == 0) ? Q : K;
      _Pragma("unroll") for (int mf = 0; mf < 4; mf++) {
        _Pragma("unroll") for (int r = 0; r < 4; r++) {
          int row = mt * 128 + wm * 64 + mf * 16 + hi * 4 + r;  // token
          int b = row >> 13;
          int tok = row & 8191;
          _Pragma("unroll") for (int nf = 0; nf < 4; nf++) {
            int col = nt * 256 + wn * 64 + nf * 16 + l15;        // channel
            int h = col >> 6;
            int d = col & 63;
            Dst[((size_t)(b * 16 + h) * 8192 + tok) * 64 + d] =
                __float2bfloat16(acc[mf][nf][r]);
          }
        }
      }
    } else {
      _Pragma("unroll") for (int mf = 0; mf < 4; mf++) {
        _Pragma("unroll") for (int r = 0; r < 4; r++) {
          int ch = mt * 128 + wm * 64 + mf * 16 + hi * 4 + r;    // channel
          int h = ch >> 6;
          int d = ch & 63;
          _Pragma("unroll") for (int nf = 0; nf < 4; nf++) {
            int tok = nt * 256 + wn * 64 + nf * 16 + l15;        // token
            int b = tok >> 13;
            int t2 = tok & 8191;
            VT[((size_t)(b * 16 + h) * 64 + d) * 8192 + t2] =
                __float2bfloat16(acc[mf][nf][r]);
          }
        }
      }
    }
  })
}

__global__ __launch_bounds__(512, 2) void k_out_gemm(
    const bf16* __restrict__ A, const bf16* __restrict__ Wo,
    float* __restrict__ Out) {
  int bid = blockIdx.x;
  int mt = bid & 63;
  int nt = bid >> 6;
  const bf16* Abase = A + (size_t)mt * 256 * 1024;
  const bf16* Bbase = Wo + (size_t)nt * 256 * 1024;
  GEMM_BODY256({
    _Pragma("unroll") for (int mf = 0; mf < 8; mf++) {
      _Pragma("unroll") for (int r = 0; r < 4; r++) {
        int row = mt * 256 + wm * 128 + mf * 16 + hi * 4 + r;
        _Pragma("unroll") for (int nf = 0; nf < 4; nf++) {
          int col = nt * 256 + wn * 64 + nf * 16 + l15;
          Out[(size_t)row * 1024 + col] = acc[mf][nf][r];
        }
      }
    }
  })
}

// ---------------- sliding-window attention (Q-tile 128, 8 waves) -----------
// Best-measured config (benched Round 17, 272.9us total): 2-slot K/V
// double-buffer, stage-at-top / drain-barrier-at-bottom, STATIC-MAX softmax,
// P via per-wave LDS buffer (ds_write/ds_read_b128 — faster than bpermute
// shuffles, R19 measured), V^T LDS reads with XOR swizzle.
__global__ __launch_bounds__(512) void k_attn(
    const bf16* __restrict__ Q, const bf16* __restrict__ K,
    const bf16* __restrict__ VT, bf16* __restrict__ ATT) {
  const int T = 8192;
  __shared__ bf16 Ks[2][64 * 64];
  __shared__ bf16 Vs[2][64 * 64];  // V^T chunk: [d][j]
  __shared__ bf16 Ps[8][16 * 64];  // per-wave P
  int bid = blockIdx.x;
  int qt = bid & 63;
  int bh = bid >> 6;  // 0..31
  int b = bh >> 4, h = bh & 15;
  int tid = threadIdx.x;
  int lane = tid & 63, wid = tid >> 6;
  int l15 = lane & 15, hi = lane >> 4;
  int q0 = qt * 128;
  int qw = q0 + wid * 16;

  short8 bq[2];
  const bf16* qp = Q + ((size_t)bh * T + qw + l15) * 64 + hi * 8;
  bq[0] = *(const short8*)qp;
  bq[1] = *(const short8*)(qp + 32);

  const bf16* Kbh = K + (size_t)bh * T * 64;
  const bf16* Vbh = VT + (size_t)bh * 64 * T;

  auto stage = [&](int bb, int c0) {
    int p = tid;  // 512 threads x 16B = 8KB per buffer
    int row = p >> 3;
    int u = (p & 7) ^ (row & 7);
    gl16(Kbh + ((size_t)(c0 + row)) * 64 + u * 8, (char*)(&Ks[bb][0]) + p * 16);
    gl16(Vbh + (size_t)row * T + c0 + u * 8, (char*)(&Vs[bb][0]) + p * 16);
  };

  int cstart = q0 - 512; if (cstart < 0) cstart = 0;
  int nch = (q0 + 128 - cstart) >> 6;

  f32x4 oacc[4];
#pragma unroll
  for (int c = 0; c < 4; c++) oacc[c] = (f32x4){0.f, 0.f, 0.f, 0.f};
  float ssum = 0.f;

  stage(0, cstart);
  __syncthreads();
  int buf = 0;
  for (int ci = 0; ci < nch; ci++) {
    int c0 = cstart + (ci << 6);
    if (ci + 1 < nch) stage(buf ^ 1, c0 + 64);
    f32x4 sacc[4];
#pragma unroll
    for (int ks = 0; ks < 4; ks++) sacc[ks] = (f32x4){0.f, 0.f, 0.f, 0.f};
#pragma unroll
    for (int dh = 0; dh < 2; dh++) {
#pragma unroll
      for (int ks = 0; ks < 4; ks++) {
        int krow = ks * 16 + l15;
        int boff = ((krow * 64 + dh * 32 + hi * 8) * 2) ^ ((krow & 7) << 4);
        short8 ak = *(const short8*)((const char*)(&Ks[buf][0]) + boff);
        sacc[ks] = __builtin_amdgcn_mfma_f32_16x16x32_bf16(ak, bq[dh], sacc[ks], 0, 0, 0);
      }
    }
    // static-max softmax: p = exp(s*0.125 - 12), masked to window
    float pv[4][4];
    float psum = 0.f;
    bool fullok = (c0 + 63 <= qw) && (c0 + 512 >= qw + 16);  // wave-uniform
    if (fullok) {
#pragma unroll
      for (int ks = 0; ks < 4; ks++)
#pragma unroll
        for (int r = 0; r < 4; r++) {
          float p = __expf(fmaf(sacc[ks][r], 0.125f, -12.0f));
          pv[ks][r] = p;
          psum += p;
        }
    } else {
      int qg = qw + l15;
#pragma unroll
      for (int ks = 0; ks < 4; ks++)
#pragma unroll
        for (int r = 0; r < 4; r++) {
          int jg = c0 + ks * 16 + hi * 4 + r;
          float p = __expf(fmaf(sacc[ks][r], 0.125f, -12.0f));
          p = ((jg <= qg) && (jg > qg - 512)) ? p : 0.f;
          pv[ks][r] = p;
          psum += p;
        }
    }
    psum += __shfl_xor(psum, 16);
    psum += __shfl_xor(psum, 32);
    ssum += psum;
    // P -> bf16 -> per-wave LDS (swizzled), then read as MFMA-A fragments
#pragma unroll
    for (int ks = 0; ks < 4; ks++) {
      unsigned int lo = (unsigned)bfbits(pv[ks][0]) | ((unsigned)bfbits(pv[ks][1]) << 16);
      unsigned int hi2 = (unsigned)bfbits(pv[ks][2]) | ((unsigned)bfbits(pv[ks][3]) << 16);
      int j0 = ks * 16 + hi * 4;
      int a0 = ((l15 * 64 + j0) * 2) ^ ((l15 & 7) << 4);
      int a1 = ((l15 * 64 + j0 + 2) * 2) ^ ((l15 & 7) << 4);
      *(unsigned int*)((char*)(&Ps[wid][0]) + a0) = lo;
      *(unsigned int*)((char*)(&Ps[wid][0]) + a1) = hi2;
    }
    short8 ap[2];
#pragma unroll
    for (int js = 0; js < 2; js++) {
      int a = ((l15 * 64 + js * 32 + hi * 8) * 2) ^ ((l15 & 7) << 4);
      ap[js] = *(const short8*)((const char*)(&Ps[wid][0]) + a);
    }
#pragma unroll
    for (int js = 0; js < 2; js++)
#pragma unroll
      for (int c = 0; c < 4; c++) {
        int vrow = c * 16 + l15;
        int boff = ((vrow * 64 + js * 32 + hi * 8) * 2) ^ ((vrow & 7) << 4);
        short8 bv = *(const short8*)((const char*)(&Vs[buf][0]) + boff);
        oacc[c] = __builtin_amdgcn_mfma_f32_16x16x32_bf16(ap[js], bv, oacc[c], 0, 0, 0);
      }
    __syncthreads();
    buf ^= 1;
  }
  float inv = 1.f / ssum;
#pragma unroll
  for (int r = 0; r < 4; r++) {
    float f = __shfl(inv, hi * 4 + r);
    int tok = qw + hi * 4 + r;
    bf16* dst = ATT + ((size_t)b * 8192 + tok) * 1024 + h * 64;
#pragma unroll
    for (int c = 0; c < 4; c++)
      dst[c * 16 + l15] = __float2bfloat16(oacc[c][r] * f);
  }
}

extern "C" void kernel_launch(void* const* d_in, const int* in_sizes, int n_in,
                              void* d_out, int out_size, void* d_ws, size_t ws_size,
                              hipStream_t stream) {
  const float* x  = (const float*)d_in[0];
  const float* wq = (const float*)d_in[1];
  const float* wk = (const float*)d_in[2];
  const float* wv = (const float*)d_in[3];
  const float* wo = (const float*)d_in[4];
  float* out = (float*)d_out;

  char* ws = (char*)d_ws;
  const size_t SZ_X = (size_t)16384 * 1024 * 2;  // 32 MB bf16
  const size_t SZ_W = (size_t)1024 * 1024 * 2;   // 2 MB bf16
  size_t off = 0;
  bf16* xb  = (bf16*)(ws + off); off += SZ_X;
  bf16* wqb = (bf16*)(ws + off); off += SZ_W;
  bf16* wkb = (bf16*)(ws + off); off += SZ_W;
  bf16* wvb = (bf16*)(ws + off); off += SZ_W;
  bf16* wob = (bf16*)(ws + off); off += SZ_W;
  bf16* qb  = (bf16*)(ws + off); off += SZ_X;
  bf16* kb  = (bf16*)(ws + off); off += SZ_X;
  bf16* vtb = (bf16*)(ws + off); off += SZ_X;
  bf16* att = xb;  // alias: x_bf16 dead after QKV GEMM

  k_cvt<<<2048, 256, 0, stream>>>(x, xb, 16384 * 1024 / 8);
  k_cvtw<<<2048, 256, 0, stream>>>(wq, wk, wv, wo, wqb, wkb, wvb, wob);
  k_qkv_gemm<<<1536, 512, 0, stream>>>(xb, wqb, wkb, wvb, qb, kb, vtb);
  k_attn<<<2048, 512, 0, stream>>>(qb, kb, vtb, att);
  k_out_gemm<<<256, 512, 0, stream>>>(att, wob, out);
}

// Round 21
// 272.197 us; speedup vs baseline: 1.0451x; 1.0353x over previous
//
#include <hip/hip_runtime.h>
#include <hip/hip_bf16.h>
#include <stdint.h>

typedef __attribute__((ext_vector_type(8))) short short8;
typedef __attribute__((ext_vector_type(4))) float f32x4;
typedef __hip_bfloat16 bf16;

#define AS1 __attribute__((address_space(1)))
#define AS3 __attribute__((address_space(3)))

__device__ __forceinline__ void gl16(const void* g, void* l) {
  __builtin_amdgcn_global_load_lds((const AS1 unsigned int*)g,
                                   (AS3 unsigned int*)l, 16, 0, 0);
}

__device__ __forceinline__ unsigned short bfbits(float x) {
  union { bf16 b; unsigned short u; } c; c.b = __float2bfloat16(x); return c.u;
}

#define SCHED0 __builtin_amdgcn_sched_barrier(0)

// ---------------- fp32 -> bf16 convert (vectorized) ----------------
__global__ __launch_bounds__(256) void k_cvt(const float* __restrict__ src,
                                             bf16* __restrict__ dst, int n8) {
  int i = blockIdx.x * blockDim.x + threadIdx.x;
  int stride = gridDim.x * blockDim.x;
  for (; i < n8; i += stride) {
    const float4* p = (const float4*)src + (size_t)i * 2;
    float4 a = p[0], b = p[1];
    bf16 tmp[8];
    tmp[0] = __float2bfloat16(a.x); tmp[1] = __float2bfloat16(a.y);
    tmp[2] = __float2bfloat16(a.z); tmp[3] = __float2bfloat16(a.w);
    tmp[4] = __float2bfloat16(b.x); tmp[5] = __float2bfloat16(b.y);
    tmp[6] = __float2bfloat16(b.z); tmp[7] = __float2bfloat16(b.w);
    *(short8*)(dst + (size_t)i * 8) = *(short8*)tmp;
  }
}

// ---- fused 4-weight fp32->bf16 convert ----
__global__ __launch_bounds__(256) void k_cvtw(
    const float* __restrict__ w0, const float* __restrict__ w1,
    const float* __restrict__ w2, const float* __restrict__ w3,
    bf16* __restrict__ d0, bf16* __restrict__ d1,
    bf16* __restrict__ d2, bf16* __restrict__ d3) {
  int gi = blockIdx.x * 256 + threadIdx.x;   // [0, 524288)
  int m = gi >> 17;
  int i = gi & 131071;
  const float* src = (m == 0) ? w0 : (m == 1) ? w1 : (m == 2) ? w2 : w3;
  bf16* dst = (m == 0) ? d0 : (m == 1) ? d1 : (m == 2) ? d2 : d3;
  const float4* p = (const float4*)src + (size_t)i * 2;
  float4 a = p[0], b = p[1];
  bf16 tmp[8];
  tmp[0] = __float2bfloat16(a.x); tmp[1] = __float2bfloat16(a.y);
  tmp[2] = __float2bfloat16(a.z); tmp[3] = __float2bfloat16(a.w);
  tmp[4] = __float2bfloat16(b.x); tmp[5] = __float2bfloat16(b.y);
  tmp[6] = __float2bfloat16(b.z); tmp[7] = __float2bfloat16(b.w);
  *(short8*)(dst + (size_t)i * 8) = *(short8*)tmp;
}

// ======== GEMM body A: 128x256 tile, BK=32, occupancy-first (qkv) =========

#define GEMM_BODY128(...)                                                      \
  const int Kd = 1024;                                                         \
  const int nk = 32;                                                           \
  __shared__ bf16 As[2][128 * 32];                                             \
  __shared__ bf16 Bs[2][256 * 32];                                             \
  int tid = threadIdx.x;                                                       \
  int lane = tid & 63, wid = tid >> 6;                                         \
  int l15 = lane & 15, hi = lane >> 4;                                         \
  int wm = wid >> 2, wn = wid & 3;                                             \
  f32x4 acc[4][4];                                                             \
  _Pragma("unroll") for (int i = 0; i < 4; i++)                                \
      _Pragma("unroll") for (int j = 0; j < 4; j++)                            \
          acc[i][j] = (f32x4){0.f, 0.f, 0.f, 0.f};                             \
  auto stage = [&](int slot, int kk) {                                         \
    const bf16* ab = Abase + kk * 32;                                          \
    const bf16* bb = Bbase + kk * 32;                                          \
    {                                                                          \
      int p = tid;                                                             \
      int row = p >> 2;                                                        \
      int u = (p & 3) ^ ((row >> 1) & 3);                                      \
      gl16(ab + (size_t)row * Kd + u * 8, (char*)(&As[slot][0]) + p * 16);     \
    }                                                                          \
    _Pragma("unroll") for (int pass = 0; pass < 2; pass++) {                   \
      int p = pass * 512 + tid;                                                \
      int row = p >> 2;                                                        \
      int u = (p & 3) ^ ((row >> 1) & 3);                                      \
      gl16(bb + (size_t)row * Kd + u * 8, (char*)(&Bs[slot][0]) + p * 16);     \
    }                                                                          \
  };                                                                           \
  stage(0, 0);                                                                 \
  asm volatile("s_waitcnt vmcnt(0)" ::: "memory");                             \
  SCHED0; __builtin_amdgcn_s_barrier(); SCHED0;                                \
  int sw = ((l15 >> 1) & 3) << 4;                                              \
  int arow = wm * 64 + l15;                                                    \
  int brow = wn * 64 + l15;                                                    \
  _Pragma("unroll 2") for (int t = 0; t < nk; ++t) {                           \
    int s = t & 1;                                                             \
    const char* Ab = (const char*)(&As[s][0]);                                 \
    const char* Bb = (const char*)(&Bs[s][0]);                                 \
    if (t + 1 < nk) stage(s ^ 1, t + 1);                                       \
    short8 af[4], bfr[4];                                                      \
    _Pragma("unroll") for (int mf = 0; mf < 4; mf++)                           \
        af[mf] = *(const short8*)(Ab +                                         \
            (((arow + mf * 16) * 64 + hi * 16) ^ sw));                         \
    _Pragma("unroll") for (int nf = 0; nf < 4; nf++)                           \
        bfr[nf] = *(const short8*)(Bb +                                        \
            (((brow + nf * 16) * 64 + hi * 16) ^ sw));                         \
    SCHED0;                                                                    \
    __builtin_amdgcn_s_setprio(1);                                             \
    _Pragma("unroll") for (int mf = 0; mf < 4; mf++)                           \
        _Pragma("unroll") for (int nf = 0; nf < 4; nf++)                       \
            acc[mf][nf] = __builtin_amdgcn_mfma_f32_16x16x32_bf16(             \
                af[mf], bfr[nf], acc[mf][nf], 0, 0, 0);                        \
    __builtin_amdgcn_s_setprio(0);                                             \
    SCHED0;                                                                    \
    if (t + 1 < nk) {                                                          \
      asm volatile("s_waitcnt vmcnt(0)" ::: "memory");                         \
      SCHED0; __builtin_amdgcn_s_barrier(); SCHED0;                            \
    }                                                                          \
  }                                                                            \
  __VA_ARGS__

// ======== GEMM body B: 256x256 tile, BK=32, 4-slot ring (out_gemm) ========

#define GEMM_BODY256(...)                                                      \
  const int Kd = 1024;                                                         \
  const int nk = 32;                                                           \
  __shared__ bf16 As[4][256 * 32];                                             \
  __shared__ bf16 Bs[4][256 * 32];                                             \
  int tid = threadIdx.x;                                                       \
  int lane = tid & 63, wid = tid >> 6;                                         \
  int l15 = lane & 15, hi = lane >> 4;                                         \
  int wm = wid >> 2, wn = wid & 3;                                             \
  f32x4 acc[8][4];                                                             \
  _Pragma("unroll") for (int i = 0; i < 8; i++)                                \
      _Pragma("unroll") for (int j = 0; j < 4; j++)                            \
          acc[i][j] = (f32x4){0.f, 0.f, 0.f, 0.f};                             \
  auto stageA = [&](int slot, int kk) {                                        \
    const bf16* ab = Abase + kk * 32;                                          \
    _Pragma("unroll") for (int pass = 0; pass < 2; pass++) {                   \
      int p = pass * 512 + tid;                                                \
      int row = p >> 2;                                                        \
      int u = (p & 3) ^ ((row >> 1) & 3);                                      \
      gl16(ab + (size_t)row * Kd + u * 8, (char*)(&As[slot][0]) + p * 16);     \
    }                                                                          \
  };                                                                           \
  auto stageB = [&](int slot, int kk) {                                        \
    const bf16* bb = Bbase + kk * 32;                                          \
    _Pragma("unroll") for (int pass = 0; pass < 2; pass++) {                   \
      int p = pass * 512 + tid;                                                \
      int row = p >> 2;                                                        \
      int u = (p & 3) ^ ((row >> 1) & 3);                                      \
      gl16(bb + (size_t)row * Kd + u * 8, (char*)(&Bs[slot][0]) + p * 16);     \
    }                                                                          \
  };                                                                           \
  stageA(0, 0); stageB(0, 0);                                                  \
  stageA(1, 1); stageB(1, 1);                                                  \
  stageA(2, 2); stageB(2, 2);                                                  \
  asm volatile("s_waitcnt vmcnt(8)" ::: "memory");                             \
  SCHED0; __builtin_amdgcn_s_barrier(); SCHED0;                                \
  int sw = ((l15 >> 1) & 3) << 4;                                              \
  int arow = wm * 128 + l15;                                                   \
  int brow = wn * 64 + l15;                                                    \
  short8 ax[4], ahi[4], bcur[4], axn[4], bn[4];                                \
  _Pragma("unroll") for (int mf = 0; mf < 4; mf++)                             \
      ax[mf] = *(const short8*)((const char*)(&As[0][0]) +                     \
                                (((arow + mf * 16) * 64 + hi * 16) ^ sw));     \
  _Pragma("unroll") for (int nf = 0; nf < 4; nf++)                             \
      bcur[nf] = *(const short8*)((const char*)(&Bs[0][0]) +                   \
                                  (((brow + nf * 16) * 64 + hi * 16) ^ sw));   \
  _Pragma("unroll 2") for (int t = 0; t < nk; ++t) {                           \
    int s = t & 3, sn = (t + 1) & 3;                                           \
    const char* Ab = (const char*)(&As[s][0]);                                 \
    _Pragma("unroll") for (int mf = 0; mf < 4; mf++)                           \
        ahi[mf] = *(const short8*)(Ab +                                        \
            (((arow + 64 + mf * 16) * 64 + hi * 16) ^ sw));                    \
    if (t + 3 < nk) stageA((t + 3) & 3, t + 3);                                \
    SCHED0;                                                                    \
    __builtin_amdgcn_s_setprio(1);                                             \
    _Pragma("unroll") for (int mf = 0; mf < 4; mf++)                           \
        _Pragma("unroll") for (int nf = 0; nf < 4; nf++)                       \
            acc[mf][nf] = __builtin_amdgcn_mfma_f32_16x16x32_bf16(             \
                ax[mf], bcur[nf], acc[mf][nf], 0, 0, 0);                       \
    __builtin_amdgcn_s_setprio(0);                                             \
    SCHED0;                                                                    \
    if (t + 1 < nk) {                                                          \
      if (t + 3 < nk)      asm volatile("s_waitcnt vmcnt(6)" ::: "memory");    \
      else if (t + 2 < nk) asm volatile("s_waitcnt vmcnt(4)" ::: "memory");    \
      else                 asm volatile("s_waitcnt vmcnt(0)" ::: "memory");    \
      SCHED0; __builtin_amdgcn_s_barrier(); SCHED0;                            \
      if (t + 3 < nk) stageB((t + 3) & 3, t + 3);                              \
      const char* AbN = (const char*)(&As[sn][0]);                             \
      const char* BbN = (const char*)(&Bs[sn][0]);                             \
      _Pragma("unroll") for (int mf = 0; mf < 4; mf++)                         \
          axn[mf] = *(const short8*)(AbN +                                     \
              (((arow + mf * 16) * 64 + hi * 16) ^ sw));                       \
      _Pragma("unroll") for (int nf = 0; nf < 4; nf++)                         \
          bn[nf] = *(const short8*)(BbN +                                      \
              (((brow + nf * 16) * 64 + hi * 16) ^ sw));                       \
      SCHED0;                                                                  \
    }                                                                          \
    __builtin_amdgcn_s_setprio(1);                                             \
    _Pragma("unroll") for (int mf = 0; mf < 4; mf++)                           \
        _Pragma("unroll") for (int nf = 0; nf < 4; nf++)                       \
            acc[mf + 4][nf] = __builtin_amdgcn_mfma_f32_16x16x32_bf16(         \
                ahi[mf], bcur[nf], acc[mf + 4][nf], 0, 0, 0);                  \
    __builtin_amdgcn_s_setprio(0);                                             \
    SCHED0;                                                                    \
    if (t + 1 < nk) {                                                          \
      __builtin_amdgcn_s_barrier(); SCHED0;                                    \
      _Pragma("unroll") for (int i = 0; i < 4; i++) {                          \
        ax[i] = axn[i]; bcur[i] = bn[i];                                       \
      }                                                                        \
    }                                                                          \
  }                                                                            \
  __VA_ARGS__

// QKV GEMM. wsel 0,1 (Q,K): A=X rows=tokens, B=W rows=channels -> C=X W^T.
// wsel 2 (V): operands swapped -> C[ch][tok] = V^T directly (no vtrans).
// V-part tile mapping mt=rem>>6, nt=rem&63: the 8 channel-tile blocks that
// share one 512KB X token-panel get bids congruent mod 8 -> SAME XCD under
// round-robin dispatch -> panel fetched once per XCD L2 (R17 had mt=rem&7,
// spreading sharers across all 8 XCDs: FETCH 181MB vs 74MB baseline).
__global__ __launch_bounds__(512, 4) void k_qkv_gemm(
    const bf16* __restrict__ X, const bf16* __restrict__ Wq,
    const bf16* __restrict__ Wk, const bf16* __restrict__ Wv,
    bf16* __restrict__ Q, bf16* __restrict__ K, bf16* __restrict__ VT) {
  int bid = blockIdx.x;
  int wsel = bid >> 9;       // 0..2 (512 blocks each)
  int rem = bid & 511;
  int mt, nt;
  const bf16 *Abase, *Bbase;
  if (wsel < 2) {
    mt = rem & 127;          // token tile (128)
    nt = rem >> 7;           // channel tile (256)
    Abase = X + (size_t)mt * 128 * 1024;
    Bbase = ((wsel == 0) ? Wq : Wk) + (size_t)nt * 256 * 1024;
  } else {
    mt = rem >> 6;           // channel tile (128): 1024/128 = 8
    nt = rem & 63;           // token tile (256): 16384/256 = 64
    Abase = Wv + (size_t)mt * 128 * 1024;
    Bbase = X + (size_t)nt * 256 * 1024;
  }
  GEMM_BODY128({
    if (wsel < 2) {
      bf16* Dst = (wsel == 0) ? Q : K;
      _Pragma("unroll") for (int mf = 0; mf < 4; mf++) {
        _Pragma("unroll") for (int r = 0; r < 4; r++) {
          int row = mt * 128 + wm * 64 + mf * 16 + hi * 4 + r;  // token
          int b = row >> 13;
          int tok = row & 8191;
          _Pragma("unroll") for (int nf = 0; nf < 4; nf++) {
            int col = nt * 256 + wn * 64 + nf * 16 + l15;        // channel
            int h = col >> 6;
            int d = col & 63;
            Dst[((size_t)(b * 16 + h) * 8192 + tok) * 64 + d] =
                __float2bfloat16(acc[mf][nf][r]);
          }
        }
      }
    } else {
      _Pragma("unroll") for (int mf = 0; mf < 4; mf++) {
        _Pragma("unroll") for (int r = 0; r < 4; r++) {
          int ch = mt * 128 + wm * 64 + mf * 16 + hi * 4 + r;    // channel
          int h = ch >> 6;
          int d = ch & 63;
          _Pragma("unroll") for (int nf = 0; nf < 4; nf++) {
            int tok = nt * 256 + wn * 64 + nf * 16 + l15;        // token
            int b = tok >> 13;
            int t2 = tok & 8191;
            VT[((size_t)(b * 16 + h) * 64 + d) * 8192 + t2] =
                __float2bfloat16(acc[mf][nf][r]);
          }
        }
      }
    }
  })
}

__global__ __launch_bounds__(512, 2) void k_out_gemm(
    const bf16* __restrict__ A, const bf16* __restrict__ Wo,
    float* __restrict__ Out) {
  int bid = blockIdx.x;
  int mt = bid & 63;
  int nt = bid >> 6;
  const bf16* Abase = A + (size_t)mt * 256 * 1024;
  const bf16* Bbase = Wo + (size_t)nt * 256 * 1024;
  GEMM_BODY256({
    _Pragma("unroll") for (int mf = 0; mf < 8; mf++) {
      _Pragma("unroll") for (int r = 0; r < 4; r++) {
        int row = mt * 256 + wm * 128 + mf * 16 + hi * 4 + r;
        _Pragma("unroll") for (int nf = 0; nf < 4; nf++) {
          int col = nt * 256 + wn * 64 + nf * 16 + l15;
          Out[(size_t)row * 1024 + col] = acc[mf][nf][r];
        }
      }
    }
  })
}

// ---------------- sliding-window attention (Q-tile 128, 8 waves) -----------
// Best-measured config: 2-slot K/V double-buffer, stage-at-top /
// drain-barrier-at-bottom, STATIC-MAX softmax, P via per-wave LDS buffer,
// V^T LDS reads with XOR swizzle.
__global__ __launch_bounds__(512) void k_attn(
    const bf16* __restrict__ Q, const bf16* __restrict__ K,
    const bf16* __restrict__ VT, bf16* __restrict__ ATT) {
  const int T = 8192;
  __shared__ bf16 Ks[2][64 * 64];
  __shared__ bf16 Vs[2][64 * 64];  // V^T chunk: [d][j]
  __shared__ bf16 Ps[8][16 * 64];  // per-wave P
  int bid = blockIdx.x;
  int qt = bid & 63;
  int bh = bid >> 6;  // 0..31
  int b = bh >> 4, h = bh & 15;
  int tid = threadIdx.x;
  int lane = tid & 63, wid = tid >> 6;
  int l15 = lane & 15, hi = lane >> 4;
  int q0 = qt * 128;
  int qw = q0 + wid * 16;

  short8 bq[2];
  const bf16* qp = Q + ((size_t)bh * T + qw + l15) * 64 + hi * 8;
  bq[0] = *(const short8*)qp;
  bq[1] = *(const short8*)(qp + 32);

  const bf16* Kbh = K + (size_t)bh * T * 64;
  const bf16* Vbh = VT + (size_t)bh * 64 * T;

  auto stage = [&](int bb, int c0) {
    int p = tid;  // 512 threads x 16B = 8KB per buffer
    int row = p >> 3;
    int u = (p & 7) ^ (row & 7);
    gl16(Kbh + ((size_t)(c0 + row)) * 64 + u * 8, (char*)(&Ks[bb][0]) + p * 16);
    gl16(Vbh + (size_t)row * T + c0 + u * 8, (char*)(&Vs[bb][0]) + p * 16);
  };

  int cstart = q0 - 512; if (cstart < 0) cstart = 0;
  int nch = (q0 + 128 - cstart) >> 6;

  f32x4 oacc[4];
#pragma unroll
  for (int c = 0; c < 4; c++) oacc[c] = (f32x4){0.f, 0.f, 0.f, 0.f};
  float ssum = 0.f;

  stage(0, cstart);
  __syncthreads();
  int buf = 0;
  for (int ci = 0; ci < nch; ci++) {
    int c0 = cstart + (ci << 6);
    if (ci + 1 < nch) stage(buf ^ 1, c0 + 64);
    f32x4 sacc[4];
#pragma unroll
    for (int ks = 0; ks < 4; ks++) sacc[ks] = (f32x4){0.f, 0.f, 0.f, 0.f};
#pragma unroll
    for (int dh = 0; dh < 2; dh++) {
#pragma unroll
      for (int ks = 0; ks < 4; ks++) {
        int krow = ks * 16 + l15;
        int boff = ((krow * 64 + dh * 32 + hi * 8) * 2) ^ ((krow & 7) << 4);
        short8 ak = *(const short8*)((const char*)(&Ks[buf][0]) + boff);
        sacc[ks] = __builtin_amdgcn_mfma_f32_16x16x32_bf16(ak, bq[dh], sacc[ks], 0, 0, 0);
      }
    }
    // static-max softmax: p = exp(s*0.125 - 12), masked to window
    float pv[4][4];
    float psum = 0.f;
    bool fullok = (c0 + 63 <= qw) && (c0 + 512 >= qw + 16);  // wave-uniform
    if (fullok) {
#pragma unroll
      for (int ks = 0; ks < 4; ks++)
#pragma unroll
        for (int r = 0; r < 4; r++) {
          float p = __expf(fmaf(sacc[ks][r], 0.125f, -12.0f));
          pv[ks][r] = p;
          psum += p;
        }
    } else {
      int qg = qw + l15;
#pragma unroll
      for (int ks = 0; ks < 4; ks++)
#pragma unroll
        for (int r = 0; r < 4; r++) {
          int jg = c0 + ks * 16 + hi * 4 + r;
          float p = __expf(fmaf(sacc[ks][r], 0.125f, -12.0f));
          p = ((jg <= qg) && (jg > qg - 512)) ? p : 0.f;
          pv[ks][r] = p;
          psum += p;
        }
    }
    psum += __shfl_xor(psum, 16);
    psum += __shfl_xor(psum, 32);
    ssum += psum;
    // P -> bf16 -> per-wave LDS (swizzled), then read as MFMA-A fragments
#pragma unroll
    for (int ks = 0; ks < 4; ks++) {
      unsigned int lo = (unsigned)bfbits(pv[ks][0]) | ((unsigned)bfbits(pv[ks][1]) << 16);
      unsigned int hi2 = (unsigned)bfbits(pv[ks][2]) | ((unsigned)bfbits(pv[ks][3]) << 16);
      int j0 = ks * 16 + hi * 4;
      int a0 = ((l15 * 64 + j0) * 2) ^ ((l15 & 7) << 4);
      int a1 = ((l15 * 64 + j0 + 2) * 2) ^ ((l15 & 7) << 4);
      *(unsigned int*)((char*)(&Ps[wid][0]) + a0) = lo;
      *(unsigned int*)((char*)(&Ps[wid][0]) + a1) = hi2;
    }
    short8 ap[2];
#pragma unroll
    for (int js = 0; js < 2; js++) {
      int a = ((l15 * 64 + js * 32 + hi * 8) * 2) ^ ((l15 & 7) << 4);
      ap[js] = *(const short8*)((const char*)(&Ps[wid][0]) + a);
    }
#pragma unroll
    for (int js = 0; js < 2; js++)
#pragma unroll
      for (int c = 0; c < 4; c++) {
        int vrow = c * 16 + l15;
        int boff = ((vrow * 64 + js * 32 + hi * 8) * 2) ^ ((vrow & 7) << 4);
        short8 bv = *(const short8*)((const char*)(&Vs[buf][0]) + boff);
        oacc[c] = __builtin_amdgcn_mfma_f32_16x16x32_bf16(ap[js], bv, oacc[c], 0, 0, 0);
      }
    __syncthreads();
    buf ^= 1;
  }
  float inv = 1.f / ssum;
#pragma unroll
  for (int r = 0; r < 4; r++) {
    float f = __shfl(inv, hi * 4 + r);
    int tok = qw + hi * 4 + r;
    bf16* dst = ATT + ((size_t)b * 8192 + tok) * 1024 + h * 64;
#pragma unroll
    for (int c = 0; c < 4; c++)
      dst[c * 16 + l15] = __float2bfloat16(oacc[c][r] * f);
  }
}

extern "C" void kernel_launch(void* const* d_in, const int* in_sizes, int n_in,
                              void* d_out, int out_size, void* d_ws, size_t ws_size,
                              hipStream_t stream) {
  const float* x  = (const float*)d_in[0];
  const float* wq = (const float*)d_in[1];
  const float* wk = (const float*)d_in[2];
  const float* wv = (const float*)d_in[3];
  const float* wo = (const float*)d_in[4];
  float* out = (float*)d_out;

  char* ws = (char*)d_ws;
  const size_t SZ_X = (size_t)16384 * 1024 * 2;  // 32 MB bf16
  const size_t SZ_W = (size_t)1024 * 1024 * 2;   // 2 MB bf16
  size_t off = 0;
  bf16* xb  = (bf16*)(ws + off); off += SZ_X;
  bf16* wqb = (bf16*)(ws + off); off += SZ_W;
  bf16* wkb = (bf16*)(ws + off); off += SZ_W;
  bf16* wvb = (bf16*)(ws + off); off += SZ_W;
  bf16* wob = (bf16*)(ws + off); off += SZ_W;
  bf16* qb  = (bf16*)(ws + off); off += SZ_X;
  bf16* kb  = (bf16*)(ws + off); off += SZ_X;
  bf16* vtb = (bf16*)(ws + off); off += SZ_X;
  bf16* att = xb;  // alias: x_bf16 dead after QKV GEMM

  k_cvt<<<2048, 256, 0, stream>>>(x, xb, 16384 * 1024 / 8);
  k_cvtw<<<2048, 256, 0, stream>>>(wq, wk, wv, wo, wqb, wkb, wvb, wob);
  k_qkv_gemm<<<1536, 512, 0, stream>>>(xb, wqb, wkb, wvb, qb, kb, vtb);
  k_attn<<<2048, 512, 0, stream>>>(qb, kb, vtb, att);
  k_out_gemm<<<256, 512, 0, stream>>>(att, wob, out);
}